// Round 12
// baseline (265.138 us; speedup 1.0000x reference)
//
#include <hip/hip_runtime.h>
#include <hip/hip_bf16.h>

#define MM 127
#define CHUNK_U16 4096        // per (matrix, k-chunk): 512 slots * 8 u16 = 8 KB
#define MAT_U16   16384       // 4 chunks per matrix = 32 KB
#define ARR_U16   1048576     // 64 matrices = 2 MB per array (X, Y)
#define QS_STRIDE 136         // per-lane stream stride (dwords)
#define SLOT_DW   (64 * QS_STRIDE)    // 8704 dwords = 34,816 B per slot
#define SLOT_U16  (SLOT_DW * 2)       // 17408 u16
#define NBIN 64

typedef __attribute__((ext_vector_type(8))) short short8;
typedef __attribute__((ext_vector_type(4))) float floatx4;

__device__ __forceinline__ void gload_lds16(const void* g, void* l) {
  __builtin_amdgcn_global_load_lds(
      (const __attribute__((address_space(1))) unsigned int*)g,
      (__attribute__((address_space(3))) unsigned int*)l, 16, 0, 0);
}

// wave_shr:1 via DPP: lane l gets lane l-1's value; lane 0 gets 0 (bound_ctrl)
__device__ __forceinline__ float wave_shr1(float x) {
  return __int_as_float(__builtin_amdgcn_update_dpp(
      0, __float_as_int(x), 0x138, 0xf, 0xf, true));
}

__device__ __forceinline__ void decode_pair(int p, int& a, int& b,
                                            int& srcA, int& srcB, float& w) {
  if (p < 4160) {
    srcA = 0;
    if (p >= 2080) { p -= 2080; srcA = 1; }
    srcB = srcA;
    int ia = (int)((sqrtf(8.0f * (float)p + 1.0f) - 1.0f) * 0.5f);
    while ((ia + 1) * (ia + 2) / 2 <= p) ia++;
    while (ia * (ia + 1) / 2 > p) ia--;
    b = p - ia * (ia + 1) / 2;
    a = ia;
    w = (a == b ? 1.0f : 2.0f) / 4096.0f;
  } else {
    p -= 4160;
    a = p >> 6; b = p & 63;
    srcA = 0; srcB = 1;
    w = -2.0f / 4096.0f;
  }
}

// ---- prep: increments -> RNE bf16, stored as the LDS frag image (R9-verified) ----
__global__ __launch_bounds__(256) void prep_kernel(
    const float* __restrict__ X, const float* __restrict__ Y,
    unsigned short* __restrict__ base, float* __restrict__ bins)
{
  if (blockIdx.x == 0 && threadIdx.x < NBIN) bins[threadIdx.x * 32] = 0.f;
  const int bid = blockIdx.x;
  const int c = bid & 3;
  const int m = (bid >> 2) & 63;
  const int isY = bid >> 8;
  const float* src = (isY ? Y : X) + m * 128 * 128;
  unsigned short* dst = base + isY * ARR_U16 + m * MAT_U16 + c * CHUNK_U16;

  for (int s = threadIdx.x; s < 512; s += 256) {
    const int r = s >> 2;
    const int g = (s & 3) ^ (r & 3);
    uint4 hv = make_uint4(0, 0, 0, 0);
    if (r < MM) {
      const float* p = src + r * 128 + c * 32 + g * 8;
      float4 u0 = *reinterpret_cast<const float4*>(p);
      float4 u1 = *reinterpret_cast<const float4*>(p + 4);
      float4 v0 = *reinterpret_cast<const float4*>(p + 128);
      float4 v1 = *reinterpret_cast<const float4*>(p + 132);
      float d[8] = {v0.x - u0.x, v0.y - u0.y, v0.z - u0.z, v0.w - u0.w,
                    v1.x - u1.x, v1.y - u1.y, v1.z - u1.z, v1.w - u1.w};
      unsigned int hw[4];
#pragma unroll
      for (int e = 0; e < 4; ++e) {
        float2 rr; rr.x = d[2 * e]; rr.y = d[2 * e + 1];
        __hip_bfloat162 hp = __float22bfloat162_rn(rr);
        unsigned int hu; __builtin_memcpy(&hu, &hp, 4);
        hw[e] = hu;
      }
      hv = make_uint4(hw[0], hw[1], hw[2], hw[3]);
    }
    *reinterpret_cast<uint4*>(dst + s * 8) = hv;
  }
}

// ---- 2 pairs/block: 2x (R11 GEMM -> stream slot), then dual-chain PDE ----
__global__ __launch_bounds__(256, 2) void sig_pair2_kernel(
    const unsigned short* __restrict__ base, float* __restrict__ bins)
{
  extern __shared__ unsigned int smw[];   // 2 * 8704 dwords = 69,632 B
  unsigned short* const sm = reinterpret_cast<unsigned short*>(smw);
  const int tid = threadIdx.x;
  const int bid = blockIdx.x;
  const int wid = tid >> 6, lane = tid & 63;
  const int row0 = (wid >> 1) * 64, col0 = (wid & 1) * 64;
  const int lrow = lane & 15, quad = lane >> 4;

  float wpair[2];

  for (int s = 0; s < 2; ++s) {
    // ---- decode pair 2*bid+s ----
    int a, b, sA, sB;
    decode_pair(2 * bid + s, a, b, sA, sB, wpair[s]);
    const unsigned short* Am = base + sA * ARR_U16 + a * MAT_U16;
    const unsigned short* Bm = base + sB * ARR_U16 + b * MAT_U16;

    const unsigned int sbase = s * SLOT_U16;   // slot s, u16 offset
    const unsigned short* gp = ((wid < 2) ? Am : Bm) + (wid & 1) * 2048 + lane * 8;
    const unsigned int dq = sbase + wid * 2048;

    floatx4 acc4[4][4];
#pragma unroll
    for (int tr = 0; tr < 4; ++tr)
#pragma unroll
      for (int tc = 0; tc < 4; ++tc) acc4[tr][tc] = (floatx4){0.f, 0.f, 0.f, 0.f};

    // preload chunk 0 into buf 0 of slot s
#pragma unroll
    for (int q = 0; q < 4; ++q)
      gload_lds16(gp + q * 512, &sm[dq + q * 512]);

    for (int c = 0; c < 4; ++c) {
      __syncthreads();   // drains DMA (vmcnt(0) before barrier)
      if (c < 3) {
        const unsigned short* g = gp + (c + 1) * CHUNK_U16;
        const unsigned int db_ = sbase + ((c + 1) & 1) * 8192 + wid * 2048;
#pragma unroll
        for (int q = 0; q < 4; ++q)
          gload_lds16(g + q * 512, &sm[db_ + q * 512]);
      }
      const unsigned int bb = sbase + (c & 1) * 8192;
      short8 bh[4];
#pragma unroll
      for (int tc = 0; tc < 4; ++tc) {
        int r = col0 + tc * 16 + lrow;
        int off = r * 32 + ((quad ^ (r & 3)) * 8);
        bh[tc] = *reinterpret_cast<const short8*>(&sm[bb + 4096 + off]);
      }
#pragma unroll
      for (int tr = 0; tr < 4; ++tr) {
        int r = row0 + tr * 16 + lrow;
        int off = r * 32 + ((quad ^ (r & 3)) * 8);
        short8 ah = *reinterpret_cast<const short8*>(&sm[bb + off]);
#pragma unroll
        for (int tc = 0; tc < 4; ++tc)
          acc4[tr][tc] = __builtin_amdgcn_mfma_f32_16x16x32_bf16(ah, bh[tc], acc4[tr][tc], 0, 0, 0);
      }
    }
    __syncthreads();   // staging reads done; slot s becomes the stream image

    // ---- zero-fill slot s (zeros = m-1 == -1 borders) ----
    for (int i = tid; i < SLOT_DW; i += 256) smw[s * SLOT_DW + i] = 0u;
    __syncthreads();

    // ---- epilogue: M (bf16) into consumer (lane, phys) slots; pk-convert ----
#pragma unroll
    for (int tr = 0; tr < 4; ++tr) {
#pragma unroll
      for (int tc = 0; tc < 4; ++tc) {
        int jm = col0 + tc * 16 + lrow;
        if (jm < MM) {
          int lt = (jm + 1) >> 1;
          int halfoff = (jm & 1) ? 0 : 1;
          int im0 = row0 + tr * 16 + quad * 4;
          int physb = im0 + jm + 5 - 4 * (lt >> 1) - 4 * (lt & 1);
          unsigned int ub = sbase + (lt * QS_STRIDE + physb) * 2 + halfoff;
#pragma unroll
          for (int ep = 0; ep < 2; ++ep) {
            float2 rr; rr.x = acc4[tr][tc][2 * ep]; rr.y = acc4[tr][tc][2 * ep + 1];
            __hip_bfloat162 bp = __float22bfloat162_rn(rr);
            unsigned int u; __builtin_memcpy(&u, &bp, 4);
            int im = im0 + 2 * ep;
            if (im < MM)     sm[ub + 2 * (2 * ep)]     = (unsigned short)u;
            if (im + 1 < MM) sm[ub + 2 * (2 * ep + 1)] = (unsigned short)(u >> 16);
          }
        }
      }
    }
    __syncthreads();
  }

  // ---- dual-chain PDE on wave (bid & 3): 2 independent pairs interleaved ----
  if (wid == (bid & 3)) {
    const int l = lane;
    const int shift = 4 * (l >> 1) + 4 * (l & 1) - 4;
    const unsigned int lbase = l * QS_STRIDE;

    auto loadg = [&](int s, int g) -> uint4 {
      int pb = 4 * g - shift;
      pb = pb < 0 ? 132 : (pb > 128 ? 128 : pb);
      return *reinterpret_cast<const uint4*>(&smw[s * SLOT_DW + lbase + pb]);
    };

    float curE[2] = {1.f, 1.f}, curO[2] = {1.f, 1.f};
    float npE[2], npO[2];
    npE[0] = npE[1] = (l == 0) ? 0.f : 1.f;
    npO[0] = npO[1] = 1.f;
    uint4 P0[2], P1[2];
    P0[0] = loadg(0, 0); P0[1] = loadg(1, 0);
    P1[0] = loadg(0, 1); P1[1] = loadg(1, 1);

    for (int g = 0; g < 63; ++g) {       // groups cover t = 0..251
      uint4 cur0 = P0[0], cur1 = P0[1];
      P0[0] = P1[0]; P0[1] = P1[1];
      if (g < 62) { P1[0] = loadg(0, g + 2); P1[1] = loadg(1, g + 2); }
      unsigned int uu0[4] = {cur0.x, cur0.y, cur0.z, cur0.w};
      unsigned int uu1[4] = {cur1.x, cur1.y, cur1.z, cur1.w};
#pragma unroll
      for (int e = 0; e < 4; ++e) {
#pragma unroll
        for (int s = 0; s < 2; ++s) {
          unsigned int u = s ? uu1[e] : uu0[e];
          float mE = __uint_as_float(u << 16) - 1.0f;
          float mO = __uint_as_float(u & 0xFFFF0000u) - 1.0f;
          float ncE = wave_shr1(curO[s]);
          float ncO = curE[s];
          float vE = (curE[s] + npE[s] * mE) + ncE;
          float vO = (curO[s] + npO[s] * mO) + ncO;
          npE[s] = ncE; npO[s] = ncO;
          curE[s] = vE; curO[s] = vO;
        }
      }
    }
    // tail: t = 252, 253 from group 63 (already in P0)
#pragma unroll
    for (int e = 0; e < 2; ++e) {
#pragma unroll
      for (int s = 0; s < 2; ++s) {
        unsigned int u = e ? (s ? P0[1].y : P0[0].y) : (s ? P0[1].x : P0[0].x);
        float mE = __uint_as_float(u << 16) - 1.0f;
        float mO = __uint_as_float(u & 0xFFFF0000u) - 1.0f;
        float ncE = wave_shr1(curO[s]);
        float ncO = curE[s];
        float vE = (curE[s] + npE[s] * mE) + ncE;
        float vO = (curO[s] + npO[s] * mO) + ncO;
        npE[s] = ncE; npO[s] = ncO;
        curE[s] = vE; curO[s] = vO;
      }
    }
    if (l == 63) {   // col 127 = odd col of lane 63; spread atomics across bins
      atomicAdd(&bins[(((bid & 31) * 2 + 0)) * 32], wpair[0] * curO[0]);
      atomicAdd(&bins[(((bid & 31) * 2 + 1)) * 32], wpair[1] * curO[1]);
    }
  }
}

__global__ void finalize_kernel(const float* __restrict__ bins,
                                unsigned int* __restrict__ out) {
  float v = 0.f;
  for (int i = 0; i < NBIN; ++i) v += bins[i * 32];
  __hip_bfloat16 bv = __float2bfloat16(v);
  unsigned short u;
  __builtin_memcpy(&u, &bv, sizeof(u));
  out[0] = ((unsigned int)u << 16) | (unsigned int)u;
}

extern "C" void kernel_launch(void* const* d_in, const int* in_sizes, int n_in,
                              void* d_out, int out_size, void* d_ws, size_t ws_size,
                              hipStream_t stream) {
  const float* X = (const float*)d_in[0];
  const float* Y = (const float*)d_in[1];
  float* bins = (float*)d_ws;                                      // 64 bins, 128 B apart
  unsigned short* base = (unsigned short*)((char*)d_ws + 16384);   // 4 MB arrays

  // opt-in to 69,632 B dynamic LDS (idempotent; R6-verified under graph capture)
  hipFuncSetAttribute(reinterpret_cast<const void*>(sig_pair2_kernel),
                      hipFuncAttributeMaxDynamicSharedMemorySize, 69632);

  prep_kernel<<<512, 256, 0, stream>>>(X, Y, base, bins);
  sig_pair2_kernel<<<4128, 256, 69632, stream>>>(base, bins);
  finalize_kernel<<<1, 1, 0, stream>>>(bins, (unsigned int*)d_out);
}